// Round 9
// baseline (5419.233 us; speedup 1.0000x reference)
//
#include <hip/hip_runtime.h>
#include <math.h>

// Problem constants
#define Bsz 32
#define Tt  512
#define Isz 256
#define Hsz 512
#define G3  1536
#define Osz 128

// Fused recurrence: 256 blocks x 512 threads, 1 block/CU, full 256-VGPR budget.
// Blocks 0..127: layer 0.  Blocks 128..255: layer 1 (computes its own input
// projection xq = Wih1 . y0[t] from register-resident Wih1).
// Block rid: p = rid&15 (cols [32p,32p+32)), bg = rid>>4 (batches 4bg..4bg+3).
// Thread: jl = tid>>4 (col), kc = tid&15 (k-chunk of 32).
// pbuf pair layout: [slot][bg][i][bi] -- the 4 batches of a group are adjacent,
// so one thread polls its element i=tid for all 4 batches with 2 dwordx4 loads.
#define TPB   512
#define NB    4
#define S0    8
#define GEN0  1u
#define CHPAD 36
#define BSTR  (16 * CHPAD)
#define POLL_GUARD (1 << 22)

typedef float f4 __attribute__((ext_vector_type(4)));
typedef unsigned int u32;
typedef u32 u32x2 __attribute__((ext_vector_type(2)));
typedef u32 u32x4 __attribute__((ext_vector_type(4)));

__device__ __forceinline__ float sigf(float x) { return 1.0f / (1.0f + expf(-x)); }

// ---------------- init: pbuf0 ring, pbuf1 double-buffer, progress ----------------
__global__ void init_bufs(u32x2* pbuf0, u32x2* pbuf1, int* prog) {
    int i = threadIdx.x + blockIdx.x * blockDim.x;
    int stride = gridDim.x * blockDim.x;
    const int n = Bsz * Hsz;
    for (int k = i; k < S0 * n; k += stride)
        pbuf0[k] = (k < n) ? (u32x2){0u, GEN0} : (u32x2){0u, 0u};
    for (int k = i; k < 2 * n; k += stride)
        pbuf1[k] = (k < n) ? (u32x2){0u, GEN0} : (u32x2){0u, 0u};
    for (int k = i; k < 128 * 16; k += stride) prog[k] = 0;
}

// ---------------- fused 2-layer persistent GRU recurrence ----------------
// Gen scheme: state at time t carries gen GEN0+t.
// L0 step t: read pbuf0 slot t&7 (gen GEN0+t) -> publish y0[t]=h0(t+1), gen
//            GEN0+t+1, slot (t+1)&7 (gated by prog back-pressure, >= t-7).
// L1 step t: read pbuf1 slot t&1 (gen GEN0+t) AND pbuf0 slot (t+1)&7 (gen
//            GEN0+t+1); publish h1(t+1), prog = t+1 after staging.
__global__ void __launch_bounds__(TPB, 1) gru_fused(
    const float* __restrict__ xp,     // [B*T,3H] layer-0 input proj (incl bih0)
    const float* __restrict__ Whh0,   // [3H,H]
    const float* __restrict__ bhh0,   // [3H]
    const float* __restrict__ Whh1,   // [3H,H]
    const float* __restrict__ Wih1,   // [3H,H]
    const float* __restrict__ bih1,   // [3H]
    const float* __restrict__ bhh1,   // [3H]
    float* __restrict__ hall,         // [B*T,H] layer-1 outputs (for FC)
    u32x2* __restrict__ pbuf0,        // [S0][B*H] pairs, packed layout
    u32x2* __restrict__ pbuf1,        // [2][B*H]  pairs, packed layout
    int*   __restrict__ prog,         // [128*16] strided
    float* __restrict__ hid)          // [2*B*H]
{
    const int tid  = threadIdx.x;
    const int role = blockIdx.x >> 7;
    const int rid  = blockIdx.x & 127;
    const int p    = rid & 15;
    const int bg   = rid >> 4;
    const int jl   = tid >> 4;          // 0..31
    const int kc   = tid & 15;          // 0..15
    const int j    = p * 32 + jl;
    const int BH   = Bsz * Hsz;
    const int grpPairs = NB * Hsz;      // pairs per bg region

    __shared__ float ldsA[NB * BSTR];
    __shared__ float ldsB[NB * BSTR];

    if (role == 0) {
        // ---- layer 0: Whh0 rows {g*H+j}, k in [32kc,+32) : 96 floats ----
        f4 w0[3][8];
        #pragma unroll
        for (int g = 0; g < 3; ++g) {
            const float* wp = Whh0 + (size_t)(g * Hsz + j) * Hsz + kc * 32;
            #pragma unroll
            for (int q = 0; q < 8; ++q) w0[g][q] = *reinterpret_cast<const f4*>(wp + q * 4);
        }
        #pragma unroll
        for (int g = 0; g < 3; ++g)
            #pragma unroll
            for (int q = 0; q < 8; ++q) asm volatile("" : "+v"(w0[g][q]));
        const float bh0 = bhh0[0 * Hsz + j];
        const float bh1 = bhh0[1 * Hsz + j];
        const float bh2 = bhh0[2 * Hsz + j];

        int bp_known = 0;

        for (int t = 0; t < Tt; ++t) {
            const u32 rg = GEN0 + (u32)t;
            const u32 wg = rg + 1u;
            const u32x2* src = pbuf0 + (size_t)(t & (S0 - 1)) * BH + bg * grpPairs;
            u32x2*       dst = pbuf0 + (size_t)((t + 1) & (S0 - 1)) * BH + bg * grpPairs;

            // xp for owner lanes
            float xr[NB], xz[NB], xn[NB];
            if (kc == 0) {
                #pragma unroll
                for (int bi = 0; bi < NB; ++bi) {
                    const float* pp = xp + (size_t)((bg * NB + bi) * Tt + t) * G3;
                    xr[bi] = pp[j]; xz[bi] = pp[Hsz + j]; xn[bi] = pp[2 * Hsz + j];
                }
            }

            // poll + stage: element tid, 4 batches = 32B = 2 dwordx4
            {
                const u32x4* sp = reinterpret_cast<const u32x4*>(src) + tid * 2;
                u32x4 r0, r1;
                int guard = 0;
                for (;;) {
                    asm volatile(
                        "global_load_dwordx4 %0, %2, off sc0 sc1\n\t"
                        "global_load_dwordx4 %1, %2, off offset:16 sc0 sc1\n\t"
                        "s_waitcnt vmcnt(0)"
                        : "=&v"(r0), "=&v"(r1)
                        : "v"(sp) : "memory");
                    bool ok = (r0[1] == rg) && (r0[3] == rg) && (r1[1] == rg) && (r1[3] == rg);
                    if (__all(ok) || ++guard > POLL_GUARD) break;
                    __builtin_amdgcn_s_sleep(1);
                }
                int li = (tid >> 5) * CHPAD + (tid & 31);
                ldsA[0 * BSTR + li] = __uint_as_float(r0[0]);
                ldsA[1 * BSTR + li] = __uint_as_float(r0[2]);
                ldsA[2 * BSTR + li] = __uint_as_float(r1[0]);
                ldsA[3 * BSTR + li] = __uint_as_float(r1[2]);
            }
            __syncthreads();

            // back-pressure BEFORE publish: need min(prog) >= t-7
            {
                const int thr = t - 7;
                if (tid < 64 && thr > bp_known) {
                    const int* pp = prog + (bg * 16 + (tid & 15)) * 16;
                    int guard = 0;
                    for (;;) {
                        int v;
                        asm volatile("global_load_dword %0, %1, off sc0 sc1\n\t"
                                     "s_waitcnt vmcnt(0)"
                                     : "=&v"(v) : "v"(pp) : "memory");
                        int mv = (tid < 16) ? v : 0x7fffffff;
                        #pragma unroll
                        for (int off = 1; off < 16; off <<= 1) {
                            int o = __shfl_xor(mv, off, 64);
                            mv = (o < mv) ? o : mv;
                        }
                        mv = __shfl(mv, 0, 64);
                        if (mv >= thr || ++guard > POLL_GUARD) { bp_known = mv; break; }
                        __builtin_amdgcn_s_sleep(2);
                    }
                }
            }
            __syncthreads();   // gate all waves' publishes

            // compute 4 batches, then packed publish
            float hv[NB];
            #pragma unroll
            for (int bi = 0; bi < NB; ++bi) {
                const f4* hp = reinterpret_cast<const f4*>(&ldsA[bi * BSTR + kc * CHPAD]);
                float a0 = 0.f, a1 = 0.f, a2 = 0.f;
                #pragma unroll
                for (int q = 0; q < 8; ++q) {
                    f4 hv4 = hp[q];
                    a0 = fmaf(w0[0][q][0], hv4[0], a0); a0 = fmaf(w0[0][q][1], hv4[1], a0);
                    a0 = fmaf(w0[0][q][2], hv4[2], a0); a0 = fmaf(w0[0][q][3], hv4[3], a0);
                    a1 = fmaf(w0[1][q][0], hv4[0], a1); a1 = fmaf(w0[1][q][1], hv4[1], a1);
                    a1 = fmaf(w0[1][q][2], hv4[2], a1); a1 = fmaf(w0[1][q][3], hv4[3], a1);
                    a2 = fmaf(w0[2][q][0], hv4[0], a2); a2 = fmaf(w0[2][q][1], hv4[1], a2);
                    a2 = fmaf(w0[2][q][2], hv4[2], a2); a2 = fmaf(w0[2][q][3], hv4[3], a2);
                }
                #pragma unroll
                for (int off = 1; off < 16; off <<= 1) {
                    a0 += __shfl_xor(a0, off, 64);
                    a1 += __shfl_xor(a1, off, 64);
                    a2 += __shfl_xor(a2, off, 64);
                }
                float rr = sigf(xr[bi] + a0 + bh0);
                float zz = sigf(xz[bi] + a1 + bh1);
                float nn = tanhf(xn[bi] + rr * (a2 + bh2));
                float ho = ldsA[bi * BSTR + p * CHPAD + jl];
                hv[bi] = (1.0f - zz) * nn + zz * ho;
            }
            if (kc == 0) {
                u32x4 pk0 = (u32x4){__float_as_uint(hv[0]), wg, __float_as_uint(hv[1]), wg};
                u32x4 pk1 = (u32x4){__float_as_uint(hv[2]), wg, __float_as_uint(hv[3]), wg};
                u32x4* dp = reinterpret_cast<u32x4*>(dst) + j * 2;
                asm volatile(
                    "global_store_dwordx4 %0, %1, off sc0 sc1\n\t"
                    "global_store_dwordx4 %0, %2, off offset:16 sc0 sc1"
                    :: "v"(dp), "v"(pk0), "v"(pk1) : "memory");
                if (t == Tt - 1) {
                    #pragma unroll
                    for (int bi = 0; bi < NB; ++bi)
                        hid[(bg * NB + bi) * Hsz + j] = hv[bi];
                }
            }
            __syncthreads();
        }
    } else {
        // ---- layer 1: Whh1 + Wih1 rows {g*H+j}, k in [32kc,+32): 192 floats ----
        f4 wh[3][8], wx[3][8];
        #pragma unroll
        for (int g = 0; g < 3; ++g) {
            const float* whp = Whh1 + (size_t)(g * Hsz + j) * Hsz + kc * 32;
            const float* wxp = Wih1 + (size_t)(g * Hsz + j) * Hsz + kc * 32;
            #pragma unroll
            for (int q = 0; q < 8; ++q) {
                wh[g][q] = *reinterpret_cast<const f4*>(whp + q * 4);
                wx[g][q] = *reinterpret_cast<const f4*>(wxp + q * 4);
            }
        }
        #pragma unroll
        for (int g = 0; g < 3; ++g)
            #pragma unroll
            for (int q = 0; q < 8; ++q) {
                asm volatile("" : "+v"(wh[g][q]));
                asm volatile("" : "+v"(wx[g][q]));
            }
        const float bi0 = bih1[0 * Hsz + j], bi1 = bih1[1 * Hsz + j], bi2 = bih1[2 * Hsz + j];
        const float bh0 = bhh1[0 * Hsz + j], bh1 = bhh1[1 * Hsz + j], bh2 = bhh1[2 * Hsz + j];

        for (int t = 0; t < Tt; ++t) {
            const u32 rg  = GEN0 + (u32)t;     // h1(t) gen
            const u32 rgp = rg + 1u;           // y0[t] gen
            const u32 wg  = rg + 1u;
            const u32x2* s1 = pbuf1 + (size_t)(t & 1) * BH + bg * grpPairs;
            const u32x2* s0 = pbuf0 + (size_t)((t + 1) & (S0 - 1)) * BH + bg * grpPairs;
            u32x2*       d1 = pbuf1 + (size_t)((t + 1) & 1) * BH + bg * grpPairs;

            // poll + stage: 2 dwordx4 from h1, 2 dwordx4 from y0
            {
                const u32x4* ap = reinterpret_cast<const u32x4*>(s1) + tid * 2;
                const u32x4* bp = reinterpret_cast<const u32x4*>(s0) + tid * 2;
                u32x4 ra0, ra1, rb0, rb1;
                int guard = 0;
                for (;;) {
                    asm volatile(
                        "global_load_dwordx4 %0, %4, off sc0 sc1\n\t"
                        "global_load_dwordx4 %1, %4, off offset:16 sc0 sc1\n\t"
                        "global_load_dwordx4 %2, %5, off sc0 sc1\n\t"
                        "global_load_dwordx4 %3, %5, off offset:16 sc0 sc1\n\t"
                        "s_waitcnt vmcnt(0)"
                        : "=&v"(ra0), "=&v"(ra1), "=&v"(rb0), "=&v"(rb1)
                        : "v"(ap), "v"(bp) : "memory");
                    bool ok = (ra0[1] == rg)  && (ra0[3] == rg)  && (ra1[1] == rg)  && (ra1[3] == rg)
                           && (rb0[1] == rgp) && (rb0[3] == rgp) && (rb1[1] == rgp) && (rb1[3] == rgp);
                    if (__all(ok) || ++guard > POLL_GUARD) break;
                    __builtin_amdgcn_s_sleep(1);
                }
                int li = (tid >> 5) * CHPAD + (tid & 31);
                ldsA[0 * BSTR + li] = __uint_as_float(ra0[0]);
                ldsA[1 * BSTR + li] = __uint_as_float(ra0[2]);
                ldsA[2 * BSTR + li] = __uint_as_float(ra1[0]);
                ldsA[3 * BSTR + li] = __uint_as_float(ra1[2]);
                ldsB[0 * BSTR + li] = __uint_as_float(rb0[0]);
                ldsB[1 * BSTR + li] = __uint_as_float(rb0[2]);
                ldsB[2 * BSTR + li] = __uint_as_float(rb1[0]);
                ldsB[3 * BSTR + li] = __uint_as_float(rb1[2]);
            }
            __syncthreads();

            // publish consumption progress (releases L0 back-pressure)
            if (tid == 0) {
                int pv = t + 1;
                asm volatile("global_store_dword %0, %1, off sc0 sc1"
                             :: "v"(prog + (bg * 16 + p) * 16), "v"(pv) : "memory");
            }

            // compute 4 batches, then packed publish
            float hv[NB];
            #pragma unroll
            for (int bi = 0; bi < NB; ++bi) {
                const f4* hA = reinterpret_cast<const f4*>(&ldsA[bi * BSTR + kc * CHPAD]);
                const f4* hB = reinterpret_cast<const f4*>(&ldsB[bi * BSTR + kc * CHPAD]);
                float g0 = 0.f, g1 = 0.f, g2 = 0.f, x0 = 0.f, x1 = 0.f, x2 = 0.f;
                #pragma unroll
                for (int q = 0; q < 8; ++q) {
                    f4 va = hA[q];
                    g0 = fmaf(wh[0][q][0], va[0], g0); g0 = fmaf(wh[0][q][1], va[1], g0);
                    g0 = fmaf(wh[0][q][2], va[2], g0); g0 = fmaf(wh[0][q][3], va[3], g0);
                    g1 = fmaf(wh[1][q][0], va[0], g1); g1 = fmaf(wh[1][q][1], va[1], g1);
                    g1 = fmaf(wh[1][q][2], va[2], g1); g1 = fmaf(wh[1][q][3], va[3], g1);
                    g2 = fmaf(wh[2][q][0], va[0], g2); g2 = fmaf(wh[2][q][1], va[1], g2);
                    g2 = fmaf(wh[2][q][2], va[2], g2); g2 = fmaf(wh[2][q][3], va[3], g2);
                    f4 vb = hB[q];
                    x0 = fmaf(wx[0][q][0], vb[0], x0); x0 = fmaf(wx[0][q][1], vb[1], x0);
                    x0 = fmaf(wx[0][q][2], vb[2], x0); x0 = fmaf(wx[0][q][3], vb[3], x0);
                    x1 = fmaf(wx[1][q][0], vb[0], x1); x1 = fmaf(wx[1][q][1], vb[1], x1);
                    x1 = fmaf(wx[1][q][2], vb[2], x1); x1 = fmaf(wx[1][q][3], vb[3], x1);
                    x2 = fmaf(wx[2][q][0], vb[0], x2); x2 = fmaf(wx[2][q][1], vb[1], x2);
                    x2 = fmaf(wx[2][q][2], vb[2], x2); x2 = fmaf(wx[2][q][3], vb[3], x2);
                }
                #pragma unroll
                for (int off = 1; off < 16; off <<= 1) {
                    g0 += __shfl_xor(g0, off, 64); g1 += __shfl_xor(g1, off, 64);
                    g2 += __shfl_xor(g2, off, 64);
                    x0 += __shfl_xor(x0, off, 64); x1 += __shfl_xor(x1, off, 64);
                    x2 += __shfl_xor(x2, off, 64);
                }
                float rr = sigf(x0 + bi0 + g0 + bh0);
                float zz = sigf(x1 + bi1 + g1 + bh1);
                float nn = tanhf(x2 + bi2 + rr * (g2 + bh2));
                float ho = ldsA[bi * BSTR + p * CHPAD + jl];
                hv[bi] = (1.0f - zz) * nn + zz * ho;
            }
            if (kc == 0) {
                u32x4 pk0 = (u32x4){__float_as_uint(hv[0]), wg, __float_as_uint(hv[1]), wg};
                u32x4 pk1 = (u32x4){__float_as_uint(hv[2]), wg, __float_as_uint(hv[3]), wg};
                u32x4* dp = reinterpret_cast<u32x4*>(d1) + j * 2;
                asm volatile(
                    "global_store_dwordx4 %0, %1, off sc0 sc1\n\t"
                    "global_store_dwordx4 %0, %2, off offset:16 sc0 sc1"
                    :: "v"(dp), "v"(pk0), "v"(pk1) : "memory");
                #pragma unroll
                for (int bi = 0; bi < NB; ++bi) {
                    hall[(size_t)((bg * NB + bi) * Tt + t) * Hsz + j] = hv[bi];
                    if (t == Tt - 1) hid[Bsz * Hsz + (bg * NB + bi) * Hsz + j] = hv[bi];
                }
            }
            __syncthreads();
        }
    }
}

// ---------------- fp32 GEMM: C[M,N] = A[M,K] * W[N,K]^T + bias[N] ----------------
#define GM 64
#define GN 64
#define GK 16
__global__ void __launch_bounds__(256) gemm_nt_bias(
    const float* __restrict__ A, const float* __restrict__ W,
    const float* __restrict__ bias, float* __restrict__ C,
    int M, int N, int K)
{
    __shared__ float As[GK][GM];
    __shared__ float Bs[GK][GN];
    const int tid = threadIdx.x;
    const int n0 = blockIdx.x * GN;
    const int m0 = blockIdx.y * GM;
    const int tn = tid & 15;
    const int tm = tid >> 4;
    const int lrow = tid >> 2;
    const int lkq  = tid & 3;

    float acc[4][4];
    #pragma unroll
    for (int i = 0; i < 4; ++i)
        #pragma unroll
        for (int jj = 0; jj < 4; ++jj) acc[i][jj] = 0.0f;

    for (int k0 = 0; k0 < K; k0 += GK) {
        float4 av = *reinterpret_cast<const float4*>(&A[(size_t)(m0 + lrow) * K + k0 + lkq * 4]);
        float4 wv = *reinterpret_cast<const float4*>(&W[(size_t)(n0 + lrow) * K + k0 + lkq * 4]);
        __syncthreads();
        As[lkq * 4 + 0][lrow] = av.x; As[lkq * 4 + 1][lrow] = av.y;
        As[lkq * 4 + 2][lrow] = av.z; As[lkq * 4 + 3][lrow] = av.w;
        Bs[lkq * 4 + 0][lrow] = wv.x; Bs[lkq * 4 + 1][lrow] = wv.y;
        Bs[lkq * 4 + 2][lrow] = wv.z; Bs[lkq * 4 + 3][lrow] = wv.w;
        __syncthreads();
        #pragma unroll
        for (int k = 0; k < GK; ++k) {
            float4 a4 = *reinterpret_cast<const float4*>(&As[k][tm * 4]);
            float4 b4 = *reinterpret_cast<const float4*>(&Bs[k][tn * 4]);
            acc[0][0] = fmaf(a4.x, b4.x, acc[0][0]); acc[0][1] = fmaf(a4.x, b4.y, acc[0][1]);
            acc[0][2] = fmaf(a4.x, b4.z, acc[0][2]); acc[0][3] = fmaf(a4.x, b4.w, acc[0][3]);
            acc[1][0] = fmaf(a4.y, b4.x, acc[1][0]); acc[1][1] = fmaf(a4.y, b4.y, acc[1][1]);
            acc[1][2] = fmaf(a4.y, b4.z, acc[1][2]); acc[1][3] = fmaf(a4.y, b4.w, acc[1][3]);
            acc[2][0] = fmaf(a4.z, b4.x, acc[2][0]); acc[2][1] = fmaf(a4.z, b4.y, acc[2][1]);
            acc[2][2] = fmaf(a4.z, b4.z, acc[2][2]); acc[2][3] = fmaf(a4.z, b4.w, acc[2][3]);
            acc[3][0] = fmaf(a4.w, b4.x, acc[3][0]); acc[3][1] = fmaf(a4.w, b4.y, acc[3][1]);
            acc[3][2] = fmaf(a4.w, b4.z, acc[3][2]); acc[3][3] = fmaf(a4.w, b4.w, acc[3][3]);
        }
    }

    float4 bb = *reinterpret_cast<const float4*>(&bias[n0 + tn * 4]);
    #pragma unroll
    for (int i = 0; i < 4; ++i) {
        int m = m0 + tm * 4 + i;
        float4 o;
        o.x = acc[i][0] + bb.x; o.y = acc[i][1] + bb.y;
        o.z = acc[i][2] + bb.z; o.w = acc[i][3] + bb.w;
        *reinterpret_cast<float4*>(&C[(size_t)m * N + n0 + tn * 4]) = o;
    }
}

// ---------------- host launcher ----------------
extern "C" void kernel_launch(void* const* d_in, const int* in_sizes, int n_in,
                              void* d_out, int out_size, void* d_ws, size_t ws_size,
                              hipStream_t stream) {
    (void)in_sizes; (void)n_in; (void)out_size; (void)ws_size;
    const float* x    = (const float*)d_in[0];
    const float* Wih0 = (const float*)d_in[1];
    const float* Whh0 = (const float*)d_in[2];
    const float* bih0 = (const float*)d_in[3];
    const float* bhh0 = (const float*)d_in[4];
    const float* Wih1 = (const float*)d_in[5];
    const float* Whh1 = (const float*)d_in[6];
    const float* bih1 = (const float*)d_in[7];
    const float* bhh1 = (const float*)d_in[8];
    const float* fcW  = (const float*)d_in[9];
    const float* fcb  = (const float*)d_in[10];

    float* out = (float*)d_out;                       // [B,T,O]
    float* hid = out + (size_t)Bsz * Tt * Osz;        // [L,B,H]

    char* ws = (char*)d_ws;
    const size_t xp_off    = 0;
    const size_t hall_off  = xp_off + (size_t)Bsz * Tt * G3 * 4;
    const size_t pbuf0_off = hall_off + (size_t)Bsz * Tt * Hsz * 4;
    const size_t pbuf1_off = pbuf0_off + (size_t)S0 * Bsz * Hsz * 8;
    const size_t prog_off  = pbuf1_off + (size_t)2 * Bsz * Hsz * 8;
    float* xp    = (float*)(ws + xp_off);
    float* hall  = (float*)(ws + hall_off);
    u32x2* pbuf0 = (u32x2*)(ws + pbuf0_off);
    u32x2* pbuf1 = (u32x2*)(ws + pbuf1_off);
    int*   prog  = (int*)  (ws + prog_off);

    // layer 0 input projection: xp = x @ Wih0^T + bih0   (M=16384, N=1536, K=256)
    hipLaunchKernelGGL(gemm_nt_bias, dim3(G3 / GN, (Bsz * Tt) / GM), dim3(256), 0, stream,
                       x, Wih0, bih0, xp, Bsz * Tt, G3, Isz);

    // init exchange buffers, then fused 2-layer recurrence
    hipLaunchKernelGGL(init_bufs, dim3(64), dim3(256), 0, stream, pbuf0, pbuf1, prog);
    hipLaunchKernelGGL(gru_fused, dim3(256), dim3(TPB), 0, stream,
                       xp, Whh0, bhh0, Whh1, Wih1, bih1, bhh1,
                       hall, pbuf0, pbuf1, prog, hid);

    // FC: out = hall @ fcW^T + fcb  (M=16384, N=128, K=512)
    hipLaunchKernelGGL(gemm_nt_bias, dim3(Osz / GN, (Bsz * Tt) / GM), dim3(256), 0, stream,
                       hall, fcW, fcb, out, Bsz * Tt, Osz, Hsz);
}

// Round 11
// 2321.961 us; speedup vs baseline: 2.3339x; 2.3339x over previous
//
#include <hip/hip_runtime.h>
#include <math.h>

// Problem constants
#define Bsz 32
#define Tt  512
#define Isz 256
#define Hsz 512
#define G3  1536
#define Osz 128

// Recurrence config (round-6 proven): 256 blocks = 32 batches x 8 col-groups;
// 512 threads/block. Exchange via device-coherent (sc0 sc1) gen-tagged pairs.
// amdgpu_waves_per_eu(2,2): grid is 1 block/CU (2 waves/SIMD) by construction,
// so pin the allocator to that occupancy -> full 256-VGPR budget -> the 192
// weight floats/thread stay register-resident instead of spilling to scratch.
#define NBLK 256
#define TPB  512
#define G0_L0 1u
#define G0_L1 4096u
#define POLL_GUARD (1 << 22)

typedef float f4  __attribute__((ext_vector_type(4)));
typedef unsigned int u32;
typedef u32 u32x2 __attribute__((ext_vector_type(2)));

__device__ __forceinline__ float sigf(float x) { return 1.0f / (1.0f + expf(-x)); }

// ---------------- init pbuf: slot0 = (h0=0, gen0), slot1 = invalid ----------------
__global__ void init_pbuf(u32x2* pbuf, u32 gen0) {
    int i = threadIdx.x + blockIdx.x * blockDim.x;
    const int n = Bsz * Hsz;
    for (; i < n; i += gridDim.x * blockDim.x) {
        pbuf[i]     = (u32x2){0u, gen0};   // slot 0: h0 = 0, valid with gen0
        pbuf[n + i] = (u32x2){0u, 0u};     // slot 1: gen invalid
    }
}

// ---------------- persistent GRU recurrence (one layer), batch-split ----------------
// Block (b,p): batch b, output h-cols [p*64, p*64+64). Thread (jl=tid>>3,
// kc=tid&7): col j=p*64+jl, k-range [kc*64, kc*64+64). 192 weight floats per
// thread, register-resident under the (2,2) waves-per-eu budget.
// Exchange per batch via (val,gen) pairs at device scope (sc0 sc1); each
// thread polls exactly one pair per step.
__global__ void __launch_bounds__(TPB)
__attribute__((amdgpu_waves_per_eu(2, 2)))
gru_rec(
    const float* __restrict__ xp,    // [B*T, 3H] (includes b_ih)
    const float* __restrict__ Whh,   // [3H, H]
    const float* __restrict__ bhh,   // [3H]
    float* __restrict__ hall,        // [B*T, H]
    u32x2* __restrict__ pbuf,        // [2][B*H] (val,gen)
    float* __restrict__ hid_out,     // [B*H] slice of d_out hidden
    u32 g0)
{
    const int tid = threadIdx.x;
    const int b   = blockIdx.x & 31;        // batch element
    const int p   = blockIdx.x >> 5;        // col-group
    const int jl  = tid >> 3;               // local col 0..63
    const int kc  = tid & 7;                // k-chunk (8 chunks of 64)
    const int j   = p * 64 + jl;            // h-col

    // h of batch b: 8 chunks of 64 floats padded to 68 (conflict-free f4 reads)
    __shared__ float hsh[8 * 68];

    // ---- load weights: rows {g*H+j}, k in [kc*64, +64)  -> 48 f4 = 192 floats ----
    f4 wreg[3][16];
    #pragma unroll
    for (int g = 0; g < 3; ++g) {
        const float* wp = Whh + (size_t)(g * Hsz + j) * Hsz + kc * 64;
        #pragma unroll
        for (int q = 0; q < 16; ++q)
            wreg[g][q] = *reinterpret_cast<const f4*>(wp + q * 4);
    }
    // keep-alive anchor (with the 256-reg budget these stay resident)
    #pragma unroll
    for (int g = 0; g < 3; ++g)
        #pragma unroll
        for (int q = 0; q < 16; ++q)
            asm volatile("" : "+v"(wreg[g][q]));

    const float bh0 = bhh[0 * Hsz + j];
    const float bh1 = bhh[1 * Hsz + j];
    const float bh2 = bhh[2 * Hsz + j];

    for (int t = 0; t < Tt; ++t) {
        const u32 rg = g0 + (u32)t;
        const u32 wg = rg + 1u;
        const u32x2* src = pbuf + (size_t)(t & 1) * (Bsz * Hsz) + b * Hsz;
        u32x2*       dst = pbuf + (size_t)((t + 1) & 1) * (Bsz * Hsz) + b * Hsz;

        // xp for owner lanes (plain cached loads; issued before poll)
        float xr = 0.f, xz = 0.f, xn = 0.f;
        if (kc == 0) {
            const float* pp = xp + (size_t)(b * Tt + t) * G3;
            xr = pp[j];
            xz = pp[Hsz + j];
            xn = pp[2 * Hsz + j];
        }

        // ---- poll own pair (1 per thread, per-wave convergence), stage to LDS ----
        {
            const u32x2* sp = src + tid;
            int guard = 0;
            for (;;) {
                u32x2 pr;
                asm volatile("global_load_dwordx2 %0, %1, off sc0 sc1\n\t"
                             "s_waitcnt vmcnt(0)"
                             : "=&v"(pr) : "v"(sp) : "memory");
                if (__all(pr[1] == rg) || ++guard > POLL_GUARD) {
                    hsh[(tid >> 6) * 68 + (tid & 63)] = __uint_as_float(pr[0]);
                    break;
                }
                __builtin_amdgcn_s_sleep(1);
            }
        }
        __syncthreads();

        // ---- compute: 3 gate partials over k in [kc*64, +64) ----
        float a0 = 0.f, a1 = 0.f, a2 = 0.f;
        {
            const f4* hp = reinterpret_cast<const f4*>(hsh) + kc * 17;  // 68/4
            #pragma unroll
            for (int q = 0; q < 16; ++q) {
                f4 hv4 = hp[q];
                a0 = fmaf(wreg[0][q][0], hv4[0], a0);
                a0 = fmaf(wreg[0][q][1], hv4[1], a0);
                a0 = fmaf(wreg[0][q][2], hv4[2], a0);
                a0 = fmaf(wreg[0][q][3], hv4[3], a0);
                a1 = fmaf(wreg[1][q][0], hv4[0], a1);
                a1 = fmaf(wreg[1][q][1], hv4[1], a1);
                a1 = fmaf(wreg[1][q][2], hv4[2], a1);
                a1 = fmaf(wreg[1][q][3], hv4[3], a1);
                a2 = fmaf(wreg[2][q][0], hv4[0], a2);
                a2 = fmaf(wreg[2][q][1], hv4[1], a2);
                a2 = fmaf(wreg[2][q][2], hv4[2], a2);
                a2 = fmaf(wreg[2][q][3], hv4[3], a2);
            }
        }

        // reduce across the 8 kc lanes (low 3 lane bits)
        #pragma unroll
        for (int off = 1; off < 8; off <<= 1) {
            a0 += __shfl_xor(a0, off, 64);
            a1 += __shfl_xor(a1, off, 64);
            a2 += __shfl_xor(a2, off, 64);
        }

        if (kc == 0) {
            float rr = sigf(xr + a0 + bh0);
            float zz = sigf(xz + a1 + bh1);
            float nn = tanhf(xn + rr * (a2 + bh2));
            float ho = hsh[(j >> 6) * 68 + (j & 63)];
            float hv = (1.0f - zz) * nn + zz * ho;
            u32x2 pk = (u32x2){__float_as_uint(hv), wg};
            asm volatile("global_store_dwordx2 %0, %1, off sc0 sc1"
                         :: "v"(dst + j), "v"(pk) : "memory");
            hall[(size_t)(b * Tt + t) * Hsz + j] = hv;       // plain
            if (t == Tt - 1) hid_out[b * Hsz + j] = hv;
        }

        __syncthreads();   // protect hsh before next step's staging
    }
}

// ---------------- fp32 GEMM: C[M,N] = A[M,K] * W[N,K]^T + bias[N] ----------------
#define GM 64
#define GN 64
#define GK 16
__global__ void __launch_bounds__(256) gemm_nt_bias(
    const float* __restrict__ A, const float* __restrict__ W,
    const float* __restrict__ bias, float* __restrict__ C,
    int M, int N, int K)
{
    __shared__ float As[GK][GM];
    __shared__ float Bs[GK][GN];
    const int tid = threadIdx.x;
    const int n0 = blockIdx.x * GN;
    const int m0 = blockIdx.y * GM;
    const int tn = tid & 15;
    const int tm = tid >> 4;
    const int lrow = tid >> 2;   // 0..63
    const int lkq  = tid & 3;    // 0..3

    float acc[4][4];
    #pragma unroll
    for (int i = 0; i < 4; ++i)
        #pragma unroll
        for (int jj = 0; jj < 4; ++jj) acc[i][jj] = 0.0f;

    for (int k0 = 0; k0 < K; k0 += GK) {
        float4 av = *reinterpret_cast<const float4*>(&A[(size_t)(m0 + lrow) * K + k0 + lkq * 4]);
        float4 wv = *reinterpret_cast<const float4*>(&W[(size_t)(n0 + lrow) * K + k0 + lkq * 4]);
        __syncthreads();
        As[lkq * 4 + 0][lrow] = av.x; As[lkq * 4 + 1][lrow] = av.y;
        As[lkq * 4 + 2][lrow] = av.z; As[lkq * 4 + 3][lrow] = av.w;
        Bs[lkq * 4 + 0][lrow] = wv.x; Bs[lkq * 4 + 1][lrow] = wv.y;
        Bs[lkq * 4 + 2][lrow] = wv.z; Bs[lkq * 4 + 3][lrow] = wv.w;
        __syncthreads();
        #pragma unroll
        for (int k = 0; k < GK; ++k) {
            float4 a4 = *reinterpret_cast<const float4*>(&As[k][tm * 4]);
            float4 b4 = *reinterpret_cast<const float4*>(&Bs[k][tn * 4]);
            acc[0][0] = fmaf(a4.x, b4.x, acc[0][0]); acc[0][1] = fmaf(a4.x, b4.y, acc[0][1]);
            acc[0][2] = fmaf(a4.x, b4.z, acc[0][2]); acc[0][3] = fmaf(a4.x, b4.w, acc[0][3]);
            acc[1][0] = fmaf(a4.y, b4.x, acc[1][0]); acc[1][1] = fmaf(a4.y, b4.y, acc[1][1]);
            acc[1][2] = fmaf(a4.y, b4.z, acc[1][2]); acc[1][3] = fmaf(a4.y, b4.w, acc[1][3]);
            acc[2][0] = fmaf(a4.z, b4.x, acc[2][0]); acc[2][1] = fmaf(a4.z, b4.y, acc[2][1]);
            acc[2][2] = fmaf(a4.z, b4.z, acc[2][2]); acc[2][3] = fmaf(a4.z, b4.w, acc[2][3]);
            acc[3][0] = fmaf(a4.w, b4.x, acc[3][0]); acc[3][1] = fmaf(a4.w, b4.y, acc[3][1]);
            acc[3][2] = fmaf(a4.w, b4.z, acc[3][2]); acc[3][3] = fmaf(a4.w, b4.w, acc[3][3]);
        }
    }

    float4 bb = *reinterpret_cast<const float4*>(&bias[n0 + tn * 4]);
    #pragma unroll
    for (int i = 0; i < 4; ++i) {
        int m = m0 + tm * 4 + i;
        float4 o;
        o.x = acc[i][0] + bb.x; o.y = acc[i][1] + bb.y;
        o.z = acc[i][2] + bb.z; o.w = acc[i][3] + bb.w;
        *reinterpret_cast<float4*>(&C[(size_t)m * N + n0 + tn * 4]) = o;
    }
}

// ---------------- host launcher ----------------
extern "C" void kernel_launch(void* const* d_in, const int* in_sizes, int n_in,
                              void* d_out, int out_size, void* d_ws, size_t ws_size,
                              hipStream_t stream) {
    (void)in_sizes; (void)n_in; (void)out_size; (void)ws_size;
    const float* x    = (const float*)d_in[0];
    const float* Wih0 = (const float*)d_in[1];
    const float* Whh0 = (const float*)d_in[2];
    const float* bih0 = (const float*)d_in[3];
    const float* bhh0 = (const float*)d_in[4];
    const float* Wih1 = (const float*)d_in[5];
    const float* Whh1 = (const float*)d_in[6];
    const float* bih1 = (const float*)d_in[7];
    const float* bhh1 = (const float*)d_in[8];
    const float* fcW  = (const float*)d_in[9];
    const float* fcb  = (const float*)d_in[10];

    float* out = (float*)d_out;                       // [B,T,O]
    float* hid = out + (size_t)Bsz * Tt * Osz;        // [L,B,H]

    char* ws = (char*)d_ws;
    const size_t xp_off   = 0;
    const size_t hall_off = xp_off + (size_t)Bsz * Tt * G3 * 4;
    const size_t pbuf_off = hall_off + (size_t)Bsz * Tt * Hsz * 4;   // 2*B*H*8B
    float* xp    = (float*)(ws + xp_off);
    float* hall  = (float*)(ws + hall_off);
    u32x2* pbuf  = (u32x2*)(ws + pbuf_off);

    // layer 0 input projection: xp = x @ Wih0^T + bih0   (M=16384, N=1536, K=256)
    hipLaunchKernelGGL(gemm_nt_bias, dim3(G3 / GN, (Bsz * Tt) / GM), dim3(256), 0, stream,
                       x, Wih0, bih0, xp, Bsz * Tt, G3, Isz);

    // init exchange buffer for layer 0, then recurrence
    hipLaunchKernelGGL(init_pbuf, dim3(64), dim3(256), 0, stream, pbuf, G0_L0);
    hipLaunchKernelGGL(gru_rec, dim3(NBLK), dim3(TPB), 0, stream,
                       xp, Whh0, bhh0, hall, pbuf, hid, G0_L0);

    // layer 1 input projection: xp = hall @ Wih1^T + bih1  (M=16384, N=1536, K=512)
    hipLaunchKernelGGL(gemm_nt_bias, dim3(G3 / GN, (Bsz * Tt) / GM), dim3(256), 0, stream,
                       hall, Wih1, bih1, xp, Bsz * Tt, G3, Hsz);

    // init exchange buffer for layer 1, then recurrence (overwrites hall)
    hipLaunchKernelGGL(init_pbuf, dim3(64), dim3(256), 0, stream, pbuf, G0_L1);
    hipLaunchKernelGGL(gru_rec, dim3(NBLK), dim3(TPB), 0, stream,
                       xp, Whh1, bhh1, hall, pbuf, hid + Bsz * Hsz, G0_L1);

    // FC: out = hall @ fcW^T + fcb  (M=16384, N=128, K=512)
    hipLaunchKernelGGL(gemm_nt_bias, dim3(Osz / GN, (Bsz * Tt) / GM), dim3(256), 0, stream,
                       hall, fcW, fcb, out, Bsz * Tt, Osz, Hsz);
}